// Round 10
// baseline (107.845 us; speedup 1.0000x reference)
//
#include <hip/hip_runtime.h>
#include <math.h>

#define NW 192
#define Wt 193
#define CHUNK 48           // k2 per block
#define NMAIN 768          // 192 k1 x 4 chunks; 512 thr -> exactly 3 blocks/CU

// cos(2*pi*num*rcpden) via HW cos (input in revolutions)
__device__ __forceinline__ float cos_revr(float num, float rcpden) {
    float rev = num * rcpden;
    rev = __builtin_amdgcn_fractf(rev);
    return __builtin_amdgcn_cosf(rev);
}

// wave-uniform broadcast from a (compile-time) lane via v_readlane -> SGPR
__device__ __forceinline__ float rdlane(float v, int l) {
    return __builtin_bit_cast(float,
        __builtin_amdgcn_readlane(__builtin_bit_cast(int, v), l));
}

// ---------------- k_fused v10: LDS-minimal ----------------
// Block b: k1 = b>>2, chunk c = b&3 (k2 in [48c,48c+48)). 512 thr = 8 waves.
// Wave w owns j in [8w, 8w+8). Lane role: p(=local k2) in phase B, i in phase D.
// Phase B: x[p][jb..jb+8) in lane p's regs: win row computed from grid
//          directly (per-lane b128, L1-dedup), M rows via wave-uniform s_load.
//          NO LDS, no barrier.
// Phase D: Chebyshev recurrence d_k = c1v*cos(k*theta): d_{k+1}=A*d_k-d_{k-1}
//          (c1v folded into seeds); xs broadcast from lane k2i via readlane
//          (compile-time lane). NO LDS reads. Only LDS use: part[8][8][64]
//          cross-wave j-reduction (16 KB), 12 barriers total.
__global__ __launch_bounds__(512, 4) void k_fused(const float* __restrict__ grid,
                                                  const float* __restrict__ Mw,
                                                  const float* __restrict__ P,
                                                  float* __restrict__ out) {
    __shared__ float part[4096];        // [w 8][k2slot 8][i 64] = 16 KB

    int bx = blockIdx.x;
    int k1  = bx >> 2;                  // 0..191
    int k2s = (bx & 3) * CHUNK;         // 0,48,96,144
    int t = threadIdx.x;
    int lane = t & 63;
    int w = __builtin_amdgcn_readfirstlane(t >> 6);   // 0..7
    int jb = w * 8;

    // ---- Phase B: x[p][j] into regs (lane = p, clamped; lanes 48-63 junk) ----
    float accj[8];
    #pragma unroll
    for (int r = 0; r < 8; ++r) accj[r] = 0.f;
    {
        int p = lane < CHUNK ? lane : CHUNK - 1;      // clamp: no OOB, junk unused
        const float* g00 = grid + ((size_t)k1 * Wt + k2s + p) * 64;
        const float* g10 = g00 + (size_t)Wt * 64;
        #pragma unroll
        for (int q = 0; q < 16; ++q) {                // c-chunks of 4
            float4 a = *(const float4*)(g00 + 4 * q);        // row k1,   col p
            float4 b = *(const float4*)(g00 + 64 + 4 * q);   // row k1,   col p+1
            float4 c = *(const float4*)(g10 + 4 * q);        // row k1+1, col p
            float4 d = *(const float4*)(g10 + 64 + 4 * q);   // row k1+1, col p+1
            float4 w4;
            w4.x = 0.25f * (a.x + b.x + c.x + d.x);
            w4.y = 0.25f * (a.y + b.y + c.y + d.y);
            w4.z = 0.25f * (a.z + b.z + c.z + d.z);
            w4.w = 0.25f * (a.w + b.w + c.w + d.w);
            #pragma unroll
            for (int r = 0; r < 8; ++r) {
                // wave-uniform address -> s_load_dwordx4 (scalar cache, L2-hot)
                const float4 m = *(const float4*)&Mw[(jb + r) * 64 + 4 * q];
                accj[r] += w4.x * m.x + w4.y * m.y + w4.z * m.z + w4.w * m.w;
            }
        }
    }

    // ---- Seeds: d_k = c1v*cos(k*theta); A = 2cos(theta). lane = i. ----
    float A[8], ce[8], co[8];
    {
        // P[i][jb..jb+8): 2 per-lane float4 loads (16 KB table, L2-hot)
        float4 pr0 = *(const float4*)&P[lane * 64 + jb];
        float4 pr1 = *(const float4*)&P[lane * 64 + jb + 4];
        float pv[8] = {pr0.x, pr0.y, pr0.z, pr0.w, pr1.x, pr1.y, pr1.z, pr1.w};
        float k1f = (float)k1, k2f = (float)k2s;
        #pragma unroll
        for (int jl = 0; jl < 8; ++jl) {
            float T  = (float)(lane * 64 + jb + jl + 2);
            float rT = __builtin_amdgcn_rcpf(T);
            A[jl]    = 2.0f * cos_revr(1.0f, rT);
            float c1 = cos_revr(k1f, rT) * pv[jl];
            ce[jl]   = cos_revr(k2f, rT) * c1;          // d_{k2s}
            co[jl]   = cos_revr(k2f - 1.0f, rT) * c1;   // d_{k2s-1}
        }
    }

    // ---- Phase D: 6 subs x 8 k2 steps; xs via readlane; part-reduce ----
    #pragma unroll
    for (int sub = 0; sub < 6; ++sub) {
        #pragma unroll
        for (int m = 0; m < 4; ++m) {
            {   // even step: current = ce, advance co
                int s = 2 * m;
                int k2i = sub * 8 + s;                  // lane holding x row
                float pa = 0.f, pb = 0.f;
                #pragma unroll
                for (int jl = 0; jl < 4; ++jl) {
                    float xs = rdlane(accj[jl], k2i);
                    pa     = fmaf(xs, ce[jl], pa);
                    co[jl] = fmaf(A[jl], ce[jl], -co[jl]);
                }
                #pragma unroll
                for (int jl = 4; jl < 8; ++jl) {
                    float xs = rdlane(accj[jl], k2i);
                    pb     = fmaf(xs, ce[jl], pb);
                    co[jl] = fmaf(A[jl], ce[jl], -co[jl]);
                }
                part[(w * 8 + s) * 64 + lane] = pa + pb;
            }
            {   // odd step: current = co, advance ce
                int s = 2 * m + 1;
                int k2i = sub * 8 + s;
                float pa = 0.f, pb = 0.f;
                #pragma unroll
                for (int jl = 0; jl < 4; ++jl) {
                    float xs = rdlane(accj[jl], k2i);
                    pa     = fmaf(xs, co[jl], pa);
                    ce[jl] = fmaf(A[jl], co[jl], -ce[jl]);
                }
                #pragma unroll
                for (int jl = 4; jl < 8; ++jl) {
                    float xs = rdlane(accj[jl], k2i);
                    pb     = fmaf(xs, co[jl], pb);
                    ce[jl] = fmaf(A[jl], co[jl], -ce[jl]);
                }
                part[(w * 8 + s) * 64 + lane] = pa + pb;
            }
        }
        __syncthreads();                // all 8 wave-partial slices written
        {   // reduce 8 wave-partials; 512 thr = one (k2slot,i) each; coalesced
            float r = part[t];
            #pragma unroll
            for (int ww = 1; ww < 8; ++ww) r += part[ww * 512 + t];
            out[((size_t)k1 * NW + (k2s + sub * 8 + (t >> 6))) * 64 + (t & 63)] = r;
        }
        __syncthreads();                // part reusable next sub
    }
}

extern "C" void kernel_launch(void* const* d_in, const int* in_sizes, int n_in,
                              void* d_out, int out_size, void* d_ws, size_t ws_size,
                              hipStream_t stream) {
    const float* grid = (const float*)d_in[0];   // [193,193,64]
    const float* Mw   = (const float*)d_in[1];   // [64,64]
    const float* P    = (const float*)d_in[2];   // [64,64]
    float* out = (float*)d_out;                  // [36864,64]
    (void)d_ws; (void)ws_size;                   // workspace unused

    k_fused<<<NMAIN, 512, 0, stream>>>(grid, Mw, P, out);
}

// Round 11
// 85.854 us; speedup vs baseline: 1.2561x; 1.2561x over previous
//
#include <hip/hip_runtime.h>
#include <math.h>

#define NW 192
#define Wt 193
#define CHUNK 48           // k2 per block
#define NMAIN 768          // 192 k1 x 4 chunks; 512 thr -> exactly 3 blocks/CU

// cos(2*pi*num*rcpden) via HW cos (input in revolutions)
__device__ __forceinline__ float cos_revr(float num, float rcpden) {
    float rev = num * rcpden;
    rev = __builtin_amdgcn_fractf(rev);
    return __builtin_amdgcn_cosf(rev);
}

// ---------------- k_fused v11: v9 structure + v10 wins ----------------
// Block b: k1 = b>>2, chunk c = b&3 (k2 in [48c,48c+48)). 512 thr = 8 waves.
// Wave w owns j in [8w, 8w+8). LDS: win 13KB + xls 13KB + part 16KB = 42.5KB
// -> 3 blocks/CU = 24 waves/CU (75%).
// A: win[p][c] coalesced into LDS (v9).
// B: lane=p<48: win rows from LDS; M rows via wave-uniform s_load (v10);
//    x -> xls[p][j] (LDS).
// Seeds: d_k = (cos(k1*th)*P[i][j]) * cos(k*th) folded into recurrence seeds
//    (v10); P per-lane from global.
// D: Chebyshev steps; xs via wave-uniform LDS b128 broadcast (v9, no
//    readlane); 16 fma/step; part[8][8][64] cross-wave j-reduce.
__global__ __launch_bounds__(512, 4) void k_fused(const float* __restrict__ grid,
                                                  const float* __restrict__ Mw,
                                                  const float* __restrict__ P,
                                                  float* __restrict__ out) {
    __shared__ float win[CHUNK * 68];   // [p][c], stride 68
    __shared__ float xls[CHUNK * 68];   // [p][j], stride 68
    __shared__ float part[4096];        // [w 8][k2slot 8][i 64] = 16 KB

    int bx = blockIdx.x;
    int k1  = bx >> 2;                  // 0..191
    int k2s = (bx & 3) * CHUNK;         // 0,48,96,144
    int t = threadIdx.x;
    int lane = t & 63;
    int w = __builtin_amdgcn_readfirstlane(t >> 6);   // 0..7
    int jb = w * 8;

    // ---- Phase A: window averages, coalesced (lane = channel c) ----
    {
        int c = lane;
        const float* gb  = grid + ((size_t)k1 * Wt + k2s) * 64 + c;
        const float* gb1 = gb + (size_t)Wt * 64;
        #pragma unroll
        for (int r = 0; r < 6; ++r) {
            int p = w * 6 + r;          // 8 waves x 6 = 48 positions
            float s = gb[p * 64] + gb[(p + 1) * 64]
                    + gb1[p * 64] + gb1[(p + 1) * 64];
            win[p * 68 + c] = 0.25f * s;
        }
    }
    __syncthreads();                    // sync1: win visible

    // ---- Phase B: x[p][jb..jb+8) (lane = p; M via wave-uniform s_load) ----
    if (lane < CHUNK) {
        float accj[8];
        #pragma unroll
        for (int r = 0; r < 8; ++r) accj[r] = 0.f;
        #pragma unroll
        for (int q4 = 0; q4 < 4; ++q4) {
            float4 wv0 = *(const float4*)&win[lane * 68 + q4 * 16];
            float4 wv1 = *(const float4*)&win[lane * 68 + q4 * 16 + 4];
            float4 wv2 = *(const float4*)&win[lane * 68 + q4 * 16 + 8];
            float4 wv3 = *(const float4*)&win[lane * 68 + q4 * 16 + 12];
            #pragma unroll
            for (int r = 0; r < 8; ++r) {
                // wave-uniform address -> s_load_dwordx4 (scalar cache)
                const float4* mr = (const float4*)&Mw[(jb + r) * 64 + q4 * 16];
                float4 m0 = mr[0], m1 = mr[1], m2 = mr[2], m3 = mr[3];
                accj[r] += wv0.x * m0.x + wv0.y * m0.y + wv0.z * m0.z + wv0.w * m0.w
                         + wv1.x * m1.x + wv1.y * m1.y + wv1.z * m1.z + wv1.w * m1.w
                         + wv2.x * m2.x + wv2.y * m2.y + wv2.z * m2.z + wv2.w * m2.w
                         + wv3.x * m3.x + wv3.y * m3.y + wv3.z * m3.z + wv3.w * m3.w;
            }
        }
        #pragma unroll
        for (int r = 0; r < 8; ++r)
            xls[lane * 68 + jb + r] = accj[r];
    }

    // ---- Seeds (independent of xls; overlaps phase B tail) ----
    // d_k[jl] = c1v*cos(k*theta): same 2-term recurrence, c1v folded in.
    float A[8], ce[8], co[8];
    {
        float4 pr0 = *(const float4*)&P[lane * 64 + jb];
        float4 pr1 = *(const float4*)&P[lane * 64 + jb + 4];
        float pv[8] = {pr0.x, pr0.y, pr0.z, pr0.w, pr1.x, pr1.y, pr1.z, pr1.w};
        float k1f = (float)k1, k2f = (float)k2s;
        #pragma unroll
        for (int jl = 0; jl < 8; ++jl) {
            float T  = (float)(lane * 64 + jb + jl + 2);
            float rT = __builtin_amdgcn_rcpf(T);
            A[jl]    = 2.0f * cos_revr(1.0f, rT);
            float c1 = cos_revr(k1f, rT) * pv[jl];
            ce[jl]   = cos_revr(k2f, rT) * c1;          // d_{k2s}
            co[jl]   = cos_revr(k2f - 1.0f, rT) * c1;   // d_{k2s-1}
        }
    }
    __syncthreads();                    // sync2: xls visible

    // ---- Phase D: 6 subs x 8 k2 steps; xs = uniform LDS b128 broadcast ----
    #pragma unroll
    for (int sub = 0; sub < 6; ++sub) {
        #pragma unroll
        for (int m = 0; m < 4; ++m) {
            {   // even step: current = ce, advance co
                int s = 2 * m;
                int k2i = sub * 8 + s;
                const float4* xq = (const float4*)&xls[k2i * 68 + jb];  // uniform
                float4 q0 = xq[0], q1 = xq[1];
                float xs[8] = {q0.x, q0.y, q0.z, q0.w, q1.x, q1.y, q1.z, q1.w};
                float pa = 0.f, pb = 0.f;       // two 4-deep chains
                #pragma unroll
                for (int jl = 0; jl < 4; ++jl) {
                    pa     = fmaf(xs[jl], ce[jl], pa);
                    co[jl] = fmaf(A[jl], ce[jl], -co[jl]);
                }
                #pragma unroll
                for (int jl = 4; jl < 8; ++jl) {
                    pb     = fmaf(xs[jl], ce[jl], pb);
                    co[jl] = fmaf(A[jl], ce[jl], -co[jl]);
                }
                part[(w * 8 + s) * 64 + lane] = pa + pb;
            }
            {   // odd step: current = co, advance ce
                int s = 2 * m + 1;
                int k2i = sub * 8 + s;
                const float4* xq = (const float4*)&xls[k2i * 68 + jb];  // uniform
                float4 q0 = xq[0], q1 = xq[1];
                float xs[8] = {q0.x, q0.y, q0.z, q0.w, q1.x, q1.y, q1.z, q1.w};
                float pa = 0.f, pb = 0.f;
                #pragma unroll
                for (int jl = 0; jl < 4; ++jl) {
                    pa     = fmaf(xs[jl], co[jl], pa);
                    ce[jl] = fmaf(A[jl], co[jl], -ce[jl]);
                }
                #pragma unroll
                for (int jl = 4; jl < 8; ++jl) {
                    pb     = fmaf(xs[jl], co[jl], pb);
                    ce[jl] = fmaf(A[jl], co[jl], -ce[jl]);
                }
                part[(w * 8 + s) * 64 + lane] = pa + pb;
            }
        }
        __syncthreads();                // all 8 wave-partial slices written
        {   // reduce 8 wave-partials; 512 thr = one (k2slot,i) each; coalesced
            float r = part[t];
            #pragma unroll
            for (int ww = 1; ww < 8; ++ww) r += part[ww * 512 + t];
            out[((size_t)k1 * NW + (k2s + sub * 8 + (t >> 6))) * 64 + (t & 63)] = r;
        }
        __syncthreads();                // part reusable next sub
    }
}

extern "C" void kernel_launch(void* const* d_in, const int* in_sizes, int n_in,
                              void* d_out, int out_size, void* d_ws, size_t ws_size,
                              hipStream_t stream) {
    const float* grid = (const float*)d_in[0];   // [193,193,64]
    const float* Mw   = (const float*)d_in[1];   // [64,64]
    const float* P    = (const float*)d_in[2];   // [64,64]
    float* out = (float*)d_out;                  // [36864,64]
    (void)d_ws; (void)ws_size;                   // workspace unused

    k_fused<<<NMAIN, 512, 0, stream>>>(grid, Mw, P, out);
}